// Round 1
// baseline (142.900 us; speedup 1.0000x reference)
//
#include <hip/hip_runtime.h>

// SmoothSkeletonDual: soft-morphology skeleton.
// dilate(x) = alpha*(logsumexp(patch/alpha) - log 9)   [softmax+entropy identity]
// erode(x)  = -dilate(-x)
// skel = sum_{k=0}^{10} clip(e_k - dilate(e_{k+1}), 0, 1),  e_k = erode^k(x)

#define HH 1024
#define WW 1024
#define NB 2

// alpha = 0.05
__device__ constexpr float C1 = 28.85390081777927f;   // 1/(alpha*ln2): exp((p-m)/a) = exp2((p-m)*C1)
__device__ constexpr float C2 = 0.03465735902799726f; // alpha*ln2:     a*ln(s) = C2*log2(s)
__device__ constexpr float C3 = 0.10986122886681098f; // alpha*ln(9)

__device__ __forceinline__ void load9(const float* __restrict__ p, int x, int y,
                                      float v[9]) {
    int xm = (x == 0) ? 1 : x - 1;
    int xp = (x == WW - 1) ? WW - 2 : x + 1;
    int ym = (y == 0) ? 1 : y - 1;
    int yp = (y == HH - 1) ? HH - 2 : y + 1;
    const float* r0 = p + (size_t)ym * WW;
    const float* r1 = p + (size_t)y  * WW;
    const float* r2 = p + (size_t)yp * WW;
    v[0] = r0[xm]; v[1] = r0[x]; v[2] = r0[xp];
    v[3] = r1[xm]; v[4] = r1[x]; v[5] = r1[xp];
    v[6] = r2[xm]; v[7] = r2[x]; v[8] = r2[xp];
}

// erode: out = mn - C2*log2( sum exp2((mn - v)*C1) ) + C3
__global__ __launch_bounds__(256) void erode_k(const float* __restrict__ in,
                                               float* __restrict__ out) {
    int x = blockIdx.x * 64 + threadIdx.x;
    int y = blockIdx.y * 4 + threadIdx.y;
    int b = blockIdx.z;
    const float* p = in + (size_t)b * HH * WW;
    float v[9];
    load9(p, x, y, v);
    float mn = v[0];
    #pragma unroll
    for (int i = 1; i < 9; ++i) mn = fminf(mn, v[i]);
    float s = 0.f;
    #pragma unroll
    for (int i = 0; i < 9; ++i) s += __builtin_amdgcn_exp2f((mn - v[i]) * C1);
    float r = mn - C2 * __builtin_amdgcn_logf(s) + C3;
    out[(size_t)b * HH * WW + (size_t)y * WW + x] = r;
}

// dilate(e) then skel (+)= clip(xc - dilate(e), 0, 1)
template <bool FIRST>
__global__ __launch_bounds__(256) void dilacc_k(const float* __restrict__ e,
                                                const float* __restrict__ xc,
                                                float* __restrict__ skel) {
    int x = blockIdx.x * 64 + threadIdx.x;
    int y = blockIdx.y * 4 + threadIdx.y;
    int b = blockIdx.z;
    const float* p = e + (size_t)b * HH * WW;
    float v[9];
    load9(p, x, y, v);
    float mx = v[0];
    #pragma unroll
    for (int i = 1; i < 9; ++i) mx = fmaxf(mx, v[i]);
    float s = 0.f;
    #pragma unroll
    for (int i = 0; i < 9; ++i) s += __builtin_amdgcn_exp2f((v[i] - mx) * C1);
    float o = mx + C2 * __builtin_amdgcn_logf(s) - C3;
    size_t idx = (size_t)b * HH * WW + (size_t)y * WW + x;
    float d = xc[idx] - o;
    d = fminf(fmaxf(d, 0.f), 1.f);
    if (FIRST)
        skel[idx] = d;
    else
        skel[idx] = skel[idx] + d;
}

extern "C" void kernel_launch(void* const* d_in, const int* in_sizes, int n_in,
                              void* d_out, int out_size, void* d_ws, size_t ws_size,
                              hipStream_t stream) {
    const float* x0 = (const float*)d_in[0];
    float* skel = (float*)d_out;
    float* bufA = (float*)d_ws;                       // e_k   (8 MB)
    float* bufB = bufA + (size_t)NB * HH * WW;        // e_k+1 (8 MB)

    dim3 blk(64, 4, 1);
    dim3 grd(WW / 64, HH / 4, NB);

    // e1 = erode(x0); skel = clip(x0 - dilate(e1))
    erode_k<<<grd, blk, 0, stream>>>(x0, bufA);
    dilacc_k<true><<<grd, blk, 0, stream>>>(bufA, x0, skel);

    float* cur = bufA;  // holds e_k
    float* nxt = bufB;
    for (int k = 1; k <= 10; ++k) {
        // e_{k+1} = erode(e_k); skel += clip(e_k - dilate(e_{k+1}))
        erode_k<<<grd, blk, 0, stream>>>(cur, nxt);
        dilacc_k<false><<<grd, blk, 0, stream>>>(nxt, cur, skel);
        float* t = cur; cur = nxt; nxt = t;
    }
}